// Round 3
// baseline (225.756 us; speedup 1.0000x reference)
//
#include <hip/hip_runtime.h>

typedef unsigned int u32;
typedef unsigned short u16;
typedef unsigned char u8;
typedef __attribute__((ext_vector_type(8))) __bf16 bf16x8;
typedef __attribute__((ext_vector_type(4))) float f32x4;
typedef __attribute__((ext_vector_type(4))) int i32x4;

#define NB 16384
#define NM 4096
#define ND 512
#define NOUT 128
#define L2E 1.44269504088896340736f

// ws layout: x_ws fp8 [rb(256)][kg64(64)][row(64)][8B]   (8 MB)
//            s_ws fp8 [mb(32)][kg64(64)][m(128)][8B]     (2 MB, pre-scaled by -2*gamma*log2e)
//            hw_ws bf16 [slab=(mb*16+kg)][o(128)][8]     (1 MB)
// x2g[16384] = gamma*log2e*||x||^2 ; s2g[4096] = gamma*log2e*||s||^2  (fp32-exact)

#define WAITLG(N) do { asm volatile("s_waitcnt vmcnt(" #N ") lgkmcnt(0)" ::: "memory"); \
                       __builtin_amdgcn_sched_barrier(0); } while (0)
#define SB0() __builtin_amdgcn_sched_barrier(0)

// ---------- helpers ----------
__device__ __forceinline__ u16 f2bf(float f) {
  u32 u = __float_as_uint(f);
  u += 0x7FFFu + ((u >> 16) & 1u);   // RNE
  return (u16)(u >> 16);
}

// manual fp32 -> e4m3fn (RNE, flush |v|<2^-6 to 0; |v| <= ~15 here so no sat needed)
__device__ __forceinline__ u8 f2fp8(float f) {
  u32 u = __float_as_uint(f);
  u32 s = (u >> 24) & 0x80u;
  u32 au = u & 0x7FFFFFFFu;
  if (au < 0x3C800000u) return (u8)s;          // below min normal -> 0
  au += 0x000FFFFFu + ((au >> 20) & 1u);       // RNE to 3 mantissa bits
  u32 e = (au >> 23) - 120u;                   // rebias 127 -> 7
  u32 m = (au >> 20) & 7u;
  return (u8)(s | (e << 3) | m);
}

__device__ __forceinline__ void stage16(const void* g, void* l) {
  __builtin_amdgcn_global_load_lds((__attribute__((address_space(1))) void*)g,
                                   (__attribute__((address_space(3))) void*)l,
                                   16, 0, 0);
}

// compiler-invisible b128 global load (keeps waitcnt pass from inserting a
// forced vmcnt stall before the gemm2 MFMA; MY counted waits cover it, since
// hardware vmcnt counts these loads too)
__device__ __forceinline__ bf16x8 ldg_b128(const void* p) {
  i32x4 r;
  asm volatile("global_load_dwordx4 %0, %1, off" : "=&v"(r) : "v"(p) : "memory");
  return __builtin_bit_cast(bf16x8, r);
}

__device__ __forceinline__ uint4 pack8bf(float4 v0, float4 v1) {
  uint4 pk;
  pk.x = (u32)f2bf(v0.x) | ((u32)f2bf(v0.y) << 16);
  pk.y = (u32)f2bf(v0.z) | ((u32)f2bf(v0.w) << 16);
  pk.z = (u32)f2bf(v1.x) | ((u32)f2bf(v1.y) << 16);
  pk.w = (u32)f2bf(v1.z) | ((u32)f2bf(v1.w) << 16);
  return pk;
}

__device__ __forceinline__ uint2 pack8f8(float4 v0, float4 v1) {
  uint2 pk;
  pk.x = (u32)f2fp8(v0.x) | ((u32)f2fp8(v0.y) << 8) |
         ((u32)f2fp8(v0.z) << 16) | ((u32)f2fp8(v0.w) << 24);
  pk.y = (u32)f2fp8(v1.x) | ((u32)f2fp8(v1.y) << 8) |
         ((u32)f2fp8(v1.z) << 16) | ((u32)f2fp8(v1.w) << 24);
  return pk;
}

// ---------- merged prep ----------
// blocks [0,512): x tiles (fp8)   [512,640): support tiles (fp8, scaled)
// [640,672): head_w (bf16)        [672,736): zero d_out (64 blocks x 128 KB)
__global__ __launch_bounds__(256) void prep_all(const float* __restrict__ x,
                                                const float* __restrict__ s,
                                                const float* __restrict__ hw,
                                                const float* __restrict__ gamma_p,
                                                u8*  __restrict__ x_ws,
                                                u8*  __restrict__ s_ws,
                                                u16* __restrict__ hw_ws,
                                                float* __restrict__ x2g,
                                                float* __restrict__ s2g,
                                                float* __restrict__ out) {
  __shared__ uint2 t8[2048];       // 16 KB (x/s transpose, XOR-swizzled)
  __shared__ uint4 t16[2048];      // 32 KB (hw transpose)
  const int tid = threadIdx.x, bid = blockIdx.x;
  const int lane = tid & 63, w = tid >> 6;

  if (bid < 640) {
    const bool isx = bid < 512;
    const int blk = isx ? bid : (bid - 512);
    const float* src_m = isx ? x : s;
    u8*    dst_ws = isx ? x_ws : s_ws;
    float* sq_out = isx ? x2g : s2g;
    const float gl   = gamma_p[0] * L2E;
    const float cmul = isx ? 1.0f : (-2.0f * gl);
    const int big  = isx ? (blk >> 1) : (blk >> 2);
    const int roff = isx ? ((blk & 1) * 32) : ((blk & 3) * 32);
    const int rows = isx ? 64 : 128;

    #pragma unroll
    for (int p = 0; p < 8; ++p) {
      const int row = p * 4 + w;                      // local row 0..31
      const float* src = src_m + (size_t)(blk * 32 + row) * ND + lane * 8;
      float4 v0 = *(const float4*)src;
      float4 v1 = *(const float4*)(src + 4);
      float ss = v0.x*v0.x + v0.y*v0.y + v0.z*v0.z + v0.w*v0.w
               + v1.x*v1.x + v1.y*v1.y + v1.z*v1.z + v1.w*v1.w;
      #pragma unroll
      for (int off = 32; off > 0; off >>= 1) ss += __shfl_down(ss, off);
      if (lane == 0) sq_out[blk * 32 + row] = gl * ss;
      v0.x *= cmul; v0.y *= cmul; v0.z *= cmul; v0.w *= cmul;
      v1.x *= cmul; v1.y *= cmul; v1.z *= cmul; v1.w *= cmul;
      t8[lane * 32 + ((row + lane) & 31)] = pack8f8(v0, v1);   // kg = lane
    }
    __syncthreads();
    #pragma unroll
    for (int p = 0; p < 8; ++p) {
      const int kg = p * 8 + (tid >> 5);
      const int row = tid & 31;
      uint2 pk = t8[kg * 32 + ((row + kg) & 31)];
      *(uint2*)&dst_ws[(((size_t)(big * 64 + kg)) * rows + roff + row) * 8] = pk;
    }
  } else if (bid < 672) {
    // ---- head_w: m-chunk of 128 (bf16) ----
    const int blk = bid - 640;
    #pragma unroll
    for (int p = 0; p < 8; ++p) {
      const int o = p * 16 + (tid >> 4);
      const int kg = tid & 15;
      const float* src = hw + (size_t)o * NM + blk * 128 + kg * 8;
      float4 v0 = *(const float4*)src;
      float4 v1 = *(const float4*)(src + 4);
      t16[o * 16 + ((kg + o) & 15)] = pack8bf(v0, v1);
    }
    __syncthreads();
    #pragma unroll
    for (int it = 0; it < 8; ++it) {
      const int kg = it * 2 + (tid >> 7);
      const int o = tid & 127;
      uint4 pk = t16[o * 16 + ((kg + o) & 15)];
      *(uint4*)&hw_ws[(((size_t)(blk * 16 + kg)) * 128 + o) * 8] = pk;
    }
  } else {
    // ---- zero d_out: 64 blocks x 128 KB ----
    float4* o4 = (float4*)out;
    const float4 z = {0.f, 0.f, 0.f, 0.f};
    size_t base = (size_t)(bid - 672) * 8192 + tid;
    #pragma unroll 8
    for (int i = 0; i < 32; ++i) o4[base + (size_t)i * 256] = z;
  }
}

// ---------- main fused kernel ----------
// R3: 512-thread blocks (8 waves), wave tile 16x64 -> 2 blocks/CU = 4 waves/SIMD.
// grid 1024: xcd = bid&7, half = xcd>>1 (M quarter), rb = (bid>>3)*2 + (xcd&1).
// X fragments in REGISTERS (32 VGPR/lane, loaded once from global) - no A ds_reads,
// no X LDS slab. LDS 48 KB static: Sbuf ring 4x8K @0 (flat-t buf = grp&3 since
// 8 grps/mt = 0 mod 4), Ks bf16 16K @32768.
// Per grp t: [8 b-frag ds_read_b64 | a2 ds_read_b128 (even, mt>0) | s2v@grp0 |
//   b2 asm-loads (odd grps, 1 ahead)] SB0; stage(t+3) (1 gload_lds/thread);
//   WAITLG(N); s_barrier; SB0; setprio(1); 8 fp8 MFMA + 4 bf16 MFMA (even,mt>0);
//   setprio(0).
// N = #vmem newer than stage(t+1) needed to guarantee it (and, at even grps, to
// drain the asm b2 issued one grp earlier - nothing else waits for asm loads):
//   grp{0,1,3}=6, {2,4}=2, 5=6|5(mt7), 6=2|0(mt7), 7=6|0(mt7).
// Epilogue barrier is lgkm(0)-only (stages for mt+1 stay in flight).
__global__ __launch_bounds__(512, 4)
void rbf_fused(const u8* __restrict__ x_ws, const u8* __restrict__ s_ws,
               const u16* __restrict__ hw_ws, const float* __restrict__ x2g,
               const float* __restrict__ s2g, const float* __restrict__ head_b,
               const float* __restrict__ scale_p, const float* __restrict__ shift_p,
               float* __restrict__ out)
{
  __shared__ __align__(16) char smem[49152];   // 48 KB

  const int tid  = threadIdx.x;
  const int w    = tid >> 6;
  const int lane = tid & 63;
  const int quad = lane >> 4;
  const int l16  = lane & 15;
  const int wr   = w & 3;    // 16-row group (0..3)
  const int wc   = w >> 2;   // 64-col half (0..1)
  const int xcd  = blockIdx.x & 7;
  const int rb   = (blockIdx.x >> 3) * 2 + (xcd & 1);
  const int half = xcd >> 1;
  const int b0   = rb * 64;

  const float vscale = scale_p[0];
  const float vshift = shift_p[0];

  const u8* xsrc = x_ws + (size_t)rb * 32768;
  const u8* ssrc = s_ws + (size_t)(half * 8) * 65536;

  auto stage_grp = [&](int mt_s, int grp_s, int buf) {
    const u8* sp = ssrc + (size_t)mt_s * 65536 + grp_s * 8192;
    stage16(sp + tid * 16, smem + buf * 8192 + tid * 16);
  };

  // ---- prologue: X fragments -> registers (16x dwordx2), x2v, S(0..2) staged ----
  long long xr[16];
  #pragma unroll
  for (int kc = 0; kc < 16; ++kc)
    xr[kc] = *(const long long*)(xsrc + ((kc * 4 + quad) * 64 + wr * 16 + l16) * 8);
  f32x4 x2v = *(const f32x4*)&x2g[b0 + wr * 16 + quad * 4];
  SB0();
  stage_grp(0, 0, 0); SB0();
  stage_grp(0, 1, 1); SB0();
  stage_grp(0, 2, 2);
  asm volatile("s_waitcnt vmcnt(2)" ::: "memory");   // X,x2v,S0 done; S1,S2 in flight
  SB0();
  __builtin_amdgcn_s_barrier();
  SB0();

  const f32x4 zf = {0.f, 0.f, 0.f, 0.f};
  f32x4 acc_xs[4], acc_out[4];
  #pragma unroll
  for (int c = 0; c < 4; ++c) { acc_xs[c] = zf; acc_out[c] = zf; }

  bf16x8 b2[4];                 // gemm2 B single-buffer (asm-loaded 1 grp ahead)

  #pragma unroll 1
  for (int mt = 0; mt < 8; ++mt) {
    const int mtg = half * 8 + mt;
    float s2v[4];

    #pragma unroll
    for (int grp = 0; grp < 8; ++grp) {
      // ---- pre-barrier region ----
      long long bf[2][4];
      #pragma unroll
      for (int k2 = 0; k2 < 2; ++k2)
        #pragma unroll
        for (int c = 0; c < 4; ++c)
          bf[k2][c] = *(const long long*)(smem + (grp & 3) * 8192 +
                                          ((k2 * 4 + quad) * 128 + wc * 64 + c * 16 + l16) * 8);
      bf16x8 a2;
      if (mt > 0 && (grp & 1) == 0) {
        const int kg = (grp >> 1) * 4 + quad;
        a2 = *(const bf16x8*)(smem + 32768 + kg * 1024 + (wr * 16 + l16) * 16);
      }
      if (grp == 0) {
        #pragma unroll
        for (int c = 0; c < 4; ++c)
          s2v[c] = s2g[mtg * 128 + wc * 64 + c * 16 + l16];
      }
      // b2 loads for the NEXT (even) grp's gemm2; dummy (clamped) at mt0 grp1/3/5
      if ((grp & 1) == 1 && !(mt == 7 && grp == 7)) {
        int ks, sm;
        if (grp < 7) { ks = (grp + 1) >> 1; sm = mtg - 1; }
        else         { ks = 0;              sm = mtg;     }
        if (sm < 0) sm = 0;
        const int kg = ks * 4 + quad;
        const size_t sb = (size_t)(sm * 16 + kg);
        #pragma unroll
        for (int c = 0; c < 4; ++c)
          b2[c] = ldg_b128(hw_ws + (sb * 128 + wc * 64 + c * 16 + l16) * 8);
      }

      SB0();   // pin region loads above, stage below (stage = newest in vm queue)

      if (grp <= 4)     stage_grp(mt, grp + 3, (grp + 3) & 3);
      else if (mt < 7)  stage_grp(mt + 1, grp - 5, (grp + 3) & 3);

      if (grp == 2 || grp == 4)  WAITLG(2);
      else if (grp == 6)         { if (mt < 7) WAITLG(2); else WAITLG(0); }
      else if (grp == 5)         { if (mt < 7) WAITLG(6); else WAITLG(5); }
      else if (grp == 7)         { if (mt < 7) WAITLG(6); else WAITLG(0); }
      else                       WAITLG(6);   // grps 0,1,3

      __builtin_amdgcn_s_barrier();
      SB0();

      // ---- post-barrier: pure-register MFMA burst ----
      __builtin_amdgcn_s_setprio(1);
      #pragma unroll
      for (int k2 = 0; k2 < 2; ++k2)
        #pragma unroll
        for (int c = 0; c < 4; ++c)
          acc_xs[c] = __builtin_amdgcn_mfma_f32_16x16x32_fp8_fp8(xr[grp * 2 + k2], bf[k2][c],
                                                                 acc_xs[c], 0, 0, 0);
      if (mt > 0 && (grp & 1) == 0) {
        #pragma unroll
        for (int c = 0; c < 4; ++c)
          acc_out[c] = __builtin_amdgcn_mfma_f32_16x16x32_bf16(a2, b2[c], acc_out[c], 0, 0, 0);
      }
      __builtin_amdgcn_s_setprio(0);
    }

    // ---- epilogue: t = acc + x2g + s2g ; k = min(exp2(-t),1) -> bf16 Ks ----
    #pragma unroll
    for (int c = 0; c < 4; ++c) {
      const int cl = wc * 64 + c * 16 + l16;       // m-col 0..127
      char* kbase = smem + 32768 + (cl >> 3) * 1024 + (cl & 7) * 2;
      #pragma unroll
      for (int i = 0; i < 4; ++i) {
        const int row = wr * 16 + quad * 4 + i;
        const float t = acc_xs[c][i] + x2v[i] + s2v[c];
        float kv = __builtin_amdgcn_exp2f(-t);
        kv = fminf(kv, 1.0f);
        *(u16*)(kbase + row * 16) = (u16)(__float_as_uint(kv) >> 16);
        acc_xs[c][i] = 0.0f;
      }
    }
    // lgkm-only barrier: Ks writes ordered before next mt's a2 reads; stages stay in flight
    asm volatile("s_waitcnt lgkmcnt(0)" ::: "memory");
    SB0();
    __builtin_amdgcn_s_barrier();
    SB0();
  }

  // ---- drained GEMM2 for the last mtile ----
  #pragma unroll
  for (int ks = 0; ks < 4; ++ks) {
    const int kg = ks * 4 + quad;
    const size_t sb = (size_t)((half * 8 + 7) * 16 + kg);
    bf16x8 bb[4];
    #pragma unroll
    for (int c = 0; c < 4; ++c)
      bb[c] = *(const bf16x8*)(hw_ws + (sb * 128 + wc * 64 + c * 16 + l16) * 8);
    bf16x8 a2 = *(const bf16x8*)(smem + 32768 + kg * 1024 + (wr * 16 + l16) * 16);
    #pragma unroll
    for (int c = 0; c < 4; ++c)
      acc_out[c] = __builtin_amdgcn_mfma_f32_16x16x32_bf16(a2, bb[c], acc_out[c], 0, 0, 0);
  }

  // ---- final: atomic-accumulate scale*acc (+ bias/shift once, by half==0 blocks) ----
  float addv[4];
  #pragma unroll
  for (int c = 0; c < 4; ++c) {
    const int col = wc * 64 + c * 16 + l16;
    addv[c] = (half == 0) ? (vscale * head_b[col] + vshift) : 0.0f;
  }
  #pragma unroll
  for (int c = 0; c < 4; ++c) {
    const int col = wc * 64 + c * 16 + l16;
    #pragma unroll
    for (int i = 0; i < 4; ++i) {
      const int row = b0 + wr * 16 + quad * 4 + i;
      atomicAdd(&out[(size_t)row * NOUT + col], vscale * acc_out[c][i] + addv[c]);
    }
  }
}

// ---------- launch ----------
extern "C" void kernel_launch(void* const* d_in, const int* in_sizes, int n_in,
                              void* d_out, int out_size, void* d_ws, size_t ws_size,
                              hipStream_t stream) {
  const float* x       = (const float*)d_in[0];
  const float* support = (const float*)d_in[1];
  const float* gamma   = (const float*)d_in[2];
  const float* head_w  = (const float*)d_in[3];
  const float* head_b  = (const float*)d_in[4];
  const float* scale   = (const float*)d_in[5];
  const float* shift   = (const float*)d_in[6];
  float* out = (float*)d_out;

  char* w = (char*)d_ws;
  u8*    x_ws  = (u8*)(w);                        //  8,388,608 B
  u8*    s_ws  = (u8*)(w + 8388608);              //  2,097,152 B
  u16*   hw_ws = (u16*)(w + 10485760);            //  1,048,576 B
  float* x2g   = (float*)(w + 11534336);          //     65,536 B
  float* s2g   = (float*)(w + 11599872);          //     16,384 B

  prep_all<<<736, 256, 0, stream>>>(x, support, head_w, gamma,
                                    x_ws, s_ws, hw_ws, x2g, s2g, out);
  rbf_fused<<<1024, 512, 0, stream>>>(x_ws, s_ws, hw_ws, x2g, s2g,
                                      head_b, scale, shift, out);
}

// Round 4
// 212.177 us; speedup vs baseline: 1.0640x; 1.0640x over previous
//
#include <hip/hip_runtime.h>

typedef unsigned int u32;
typedef unsigned short u16;
typedef unsigned char u8;
typedef __attribute__((ext_vector_type(8))) __bf16 bf16x8;
typedef __attribute__((ext_vector_type(4))) float f32x4;
typedef __attribute__((ext_vector_type(4))) int i32x4;

#define NB 16384
#define NM 4096
#define ND 512
#define NOUT 128
#define L2E 1.44269504088896340736f

// ws layout: x_ws fp8 [rb(256)][kg64(64)][row(64)][8B]   (8 MB)
//            s_ws fp8 [mb(32)][kg64(64)][m(128)][8B]     (2 MB, pre-scaled by -2*gamma*log2e)
//            hw_ws bf16 [slab=(mb*16+kg)][o(128)][8]     (1 MB)
// x2g[16384] = gamma*log2e*||x||^2 ; s2g[4096] = gamma*log2e*||s||^2  (fp32-exact)

#define WAITLG(N) do { asm volatile("s_waitcnt vmcnt(" #N ") lgkmcnt(0)" ::: "memory"); \
                       __builtin_amdgcn_sched_barrier(0); } while (0)
#define SB0() __builtin_amdgcn_sched_barrier(0)

// ---------- helpers ----------
__device__ __forceinline__ u16 f2bf(float f) {
  u32 u = __float_as_uint(f);
  u += 0x7FFFu + ((u >> 16) & 1u);   // RNE
  return (u16)(u >> 16);
}

// manual fp32 -> e4m3fn (RNE, flush |v|<2^-6 to 0; |v| <= ~15 here so no sat needed)
__device__ __forceinline__ u8 f2fp8(float f) {
  u32 u = __float_as_uint(f);
  u32 s = (u >> 24) & 0x80u;
  u32 au = u & 0x7FFFFFFFu;
  if (au < 0x3C800000u) return (u8)s;          // below min normal -> 0
  au += 0x000FFFFFu + ((au >> 20) & 1u);       // RNE to 3 mantissa bits
  u32 e = (au >> 23) - 120u;                   // rebias 127 -> 7
  u32 m = (au >> 20) & 7u;
  return (u8)(s | (e << 3) | m);
}

__device__ __forceinline__ void stage16(const void* g, void* l) {
  __builtin_amdgcn_global_load_lds((__attribute__((address_space(1))) void*)g,
                                   (__attribute__((address_space(3))) void*)l,
                                   16, 0, 0);
}

// compiler-invisible b128 global load: waitcnt pass can't see it, so no forced
// vmcnt stall before the gemm2 MFMA; MY counted waits cover it (HW vmcnt counts it)
__device__ __forceinline__ bf16x8 ldg_b128(const void* p) {
  i32x4 r;
  asm volatile("global_load_dwordx4 %0, %1, off" : "=&v"(r) : "v"(p) : "memory");
  return __builtin_bit_cast(bf16x8, r);
}

__device__ __forceinline__ uint4 pack8bf(float4 v0, float4 v1) {
  uint4 pk;
  pk.x = (u32)f2bf(v0.x) | ((u32)f2bf(v0.y) << 16);
  pk.y = (u32)f2bf(v0.z) | ((u32)f2bf(v0.w) << 16);
  pk.z = (u32)f2bf(v1.x) | ((u32)f2bf(v1.y) << 16);
  pk.w = (u32)f2bf(v1.z) | ((u32)f2bf(v1.w) << 16);
  return pk;
}

__device__ __forceinline__ uint2 pack8f8(float4 v0, float4 v1) {
  uint2 pk;
  pk.x = (u32)f2fp8(v0.x) | ((u32)f2fp8(v0.y) << 8) |
         ((u32)f2fp8(v0.z) << 16) | ((u32)f2fp8(v0.w) << 24);
  pk.y = (u32)f2fp8(v1.x) | ((u32)f2fp8(v1.y) << 8) |
         ((u32)f2fp8(v1.z) << 16) | ((u32)f2fp8(v1.w) << 24);
  return pk;
}

// ---------- merged prep ----------
// blocks [0,512): x tiles (fp8)   [512,640): support tiles (fp8, scaled)
// [640,672): head_w (bf16)        [672,736): zero d_out (64 blocks x 128 KB)
__global__ __launch_bounds__(256) void prep_all(const float* __restrict__ x,
                                                const float* __restrict__ s,
                                                const float* __restrict__ hw,
                                                const float* __restrict__ gamma_p,
                                                u8*  __restrict__ x_ws,
                                                u8*  __restrict__ s_ws,
                                                u16* __restrict__ hw_ws,
                                                float* __restrict__ x2g,
                                                float* __restrict__ s2g,
                                                float* __restrict__ out) {
  __shared__ uint2 t8[2048];       // 16 KB (x/s transpose, XOR-swizzled)
  __shared__ uint4 t16[2048];      // 32 KB (hw transpose)
  const int tid = threadIdx.x, bid = blockIdx.x;
  const int lane = tid & 63, w = tid >> 6;

  if (bid < 640) {
    const bool isx = bid < 512;
    const int blk = isx ? bid : (bid - 512);
    const float* src_m = isx ? x : s;
    u8*    dst_ws = isx ? x_ws : s_ws;
    float* sq_out = isx ? x2g : s2g;
    const float gl   = gamma_p[0] * L2E;
    const float cmul = isx ? 1.0f : (-2.0f * gl);
    const int big  = isx ? (blk >> 1) : (blk >> 2);
    const int roff = isx ? ((blk & 1) * 32) : ((blk & 3) * 32);
    const int rows = isx ? 64 : 128;

    #pragma unroll
    for (int p = 0; p < 8; ++p) {
      const int row = p * 4 + w;                      // local row 0..31
      const float* src = src_m + (size_t)(blk * 32 + row) * ND + lane * 8;
      float4 v0 = *(const float4*)src;
      float4 v1 = *(const float4*)(src + 4);
      float ss = v0.x*v0.x + v0.y*v0.y + v0.z*v0.z + v0.w*v0.w
               + v1.x*v1.x + v1.y*v1.y + v1.z*v1.z + v1.w*v1.w;
      #pragma unroll
      for (int off = 32; off > 0; off >>= 1) ss += __shfl_down(ss, off);
      if (lane == 0) sq_out[blk * 32 + row] = gl * ss;
      v0.x *= cmul; v0.y *= cmul; v0.z *= cmul; v0.w *= cmul;
      v1.x *= cmul; v1.y *= cmul; v1.z *= cmul; v1.w *= cmul;
      t8[lane * 32 + ((row + lane) & 31)] = pack8f8(v0, v1);   // kg = lane
    }
    __syncthreads();
    #pragma unroll
    for (int p = 0; p < 8; ++p) {
      const int kg = p * 8 + (tid >> 5);
      const int row = tid & 31;
      uint2 pk = t8[kg * 32 + ((row + kg) & 31)];
      *(uint2*)&dst_ws[(((size_t)(big * 64 + kg)) * rows + roff + row) * 8] = pk;
    }
  } else if (bid < 672) {
    // ---- head_w: m-chunk of 128 (bf16) ----
    const int blk = bid - 640;
    #pragma unroll
    for (int p = 0; p < 8; ++p) {
      const int o = p * 16 + (tid >> 4);
      const int kg = tid & 15;
      const float* src = hw + (size_t)o * NM + blk * 128 + kg * 8;
      float4 v0 = *(const float4*)src;
      float4 v1 = *(const float4*)(src + 4);
      t16[o * 16 + ((kg + o) & 15)] = pack8bf(v0, v1);
    }
    __syncthreads();
    #pragma unroll
    for (int it = 0; it < 8; ++it) {
      const int kg = it * 2 + (tid >> 7);
      const int o = tid & 127;
      uint4 pk = t16[o * 16 + ((kg + o) & 15)];
      *(uint4*)&hw_ws[(((size_t)(blk * 16 + kg)) * 128 + o) * 8] = pk;
    }
  } else {
    // ---- zero d_out: 64 blocks x 128 KB ----
    float4* o4 = (float4*)out;
    const float4 z = {0.f, 0.f, 0.f, 0.f};
    size_t base = (size_t)(bid - 672) * 8192 + tid;
    #pragma unroll 8
    for (int i = 0; i < 32; ++i) o4[base + (size_t)i * 256] = z;
  }
}

// ---------- main fused kernel ----------
// R4: 512-thread blocks (8 waves), wave tile 16x64; X in LDS (R2's layout; R3's
// X-in-regs spilled: VGPR clamp 64, +55MB scratch). LDS 80 KB DYNAMIC:
// X 32K @0 (resident), Sbuf ring 4x8K @32768, Ks 16K @65536 -> 2 blocks/CU =
// 16 waves/CU = 4 waves/SIMD iff VGPR<=128 (~110 expected; launch_bounds(512,2)
// keeps the allocator in R2's sane regime — (512,4) is what caused the clamp).
// Per slot t=mt*8+grp: [2 a + 8 b ds_read_b64 | a2 b128 (even,mt>0) | s2v@grp0 |
//   b2 asm x4 (odd)] SB0; stage(t+3) (1 gload_lds/thr); WAITLG(N); s_barrier;
//   SB0; setprio(1); 8 fp8 MFMA + 4 bf16 MFMA (even,mt>0); setprio(0).
// Per-thread vmem/slot: grp0=5(s2v4+St), odd=5(b2x4+St), even=1(St).
// N: even=2 (drains b2(t-1), implies St(t-2)); grp0=6 (target b2 of grp7);
// odd=7 (no-op steady; covers mt0 edges); mt7 tail: g5=7,g6=0,g7=0.
// Ring hazard (stage(t) overwrites buf read at t-1) covered by barrier(t-1)
// + lgkmcnt(0). Epilogue barrier is lgkm-only (next-mt stages stay in flight).
__global__ __launch_bounds__(512, 2)
void rbf_fused(const u8* __restrict__ x_ws, const u8* __restrict__ s_ws,
               const u16* __restrict__ hw_ws, const float* __restrict__ x2g,
               const float* __restrict__ s2g, const float* __restrict__ head_b,
               const float* __restrict__ scale_p, const float* __restrict__ shift_p,
               float* __restrict__ out)
{
  extern __shared__ __align__(16) char smem[];   // 80 KB dynamic

  const int tid  = threadIdx.x;
  const int w    = tid >> 6;
  const int lane = tid & 63;
  const int quad = lane >> 4;
  const int l16  = lane & 15;
  const int wr   = w & 3;    // 16-row group (0..3)
  const int wc   = w >> 2;   // 64-col half (0..1)
  const int xcd  = blockIdx.x & 7;
  const int rb   = (blockIdx.x >> 3) * 2 + (xcd & 1);
  const int half = xcd >> 1;
  const int b0   = rb * 64;

  const float vscale = scale_p[0];
  const float vshift = shift_p[0];

  const u8* xsrc = x_ws + (size_t)rb * 32768;
  const u8* ssrc = s_ws + (size_t)(half * 8) * 65536;

  auto stage_grp = [&](int mt_s, int grp_s) {
    const u8* sp = ssrc + (size_t)mt_s * 65536 + grp_s * 8192;
    stage16(sp + tid * 16, smem + 32768 + (grp_s & 3) * 8192 + tid * 16);
  };

  // ---- prologue: X slice -> LDS (4 stages), x2v, S(0..2); order pinned ----
  #pragma unroll
  for (int i = 0; i < 4; ++i)
    stage16(xsrc + i * 8192 + tid * 16, smem + i * 8192 + tid * 16);
  SB0();
  f32x4 x2v = *(const f32x4*)&x2g[b0 + wr * 16 + quad * 4];
  SB0();
  stage_grp(0, 0); SB0();
  stage_grp(0, 1); SB0();
  stage_grp(0, 2);
  asm volatile("s_waitcnt vmcnt(2)" ::: "memory");   // X,x2v,S0 done; S1,S2 in flight
  SB0();
  __builtin_amdgcn_s_barrier();
  SB0();

  const f32x4 zf = {0.f, 0.f, 0.f, 0.f};
  f32x4 acc_xs[4], acc_out[4];
  #pragma unroll
  for (int c = 0; c < 4; ++c) { acc_xs[c] = zf; acc_out[c] = zf; }

  bf16x8 b2[4];                 // gemm2 B single-buffer (asm-loaded 1 slot ahead)

  #pragma unroll 1
  for (int mt = 0; mt < 8; ++mt) {
    const int mtg = half * 8 + mt;
    float s2v[4];

    #pragma unroll
    for (int grp = 0; grp < 8; ++grp) {
      // ---- pre-barrier region ----
      long long a[2], bf[2][4];
      #pragma unroll
      for (int k2 = 0; k2 < 2; ++k2) {
        const int kc = grp * 2 + k2;
        a[k2] = *(const long long*)(smem + ((kc * 4 + quad) * 64 + wr * 16 + l16) * 8);
        #pragma unroll
        for (int c = 0; c < 4; ++c)
          bf[k2][c] = *(const long long*)(smem + 32768 + (grp & 3) * 8192 +
                                          ((k2 * 4 + quad) * 128 + wc * 64 + c * 16 + l16) * 8);
      }
      bf16x8 a2;
      if (mt > 0 && (grp & 1) == 0) {
        const int kg = (grp >> 1) * 4 + quad;
        a2 = *(const bf16x8*)(smem + 65536 + kg * 1024 + (wr * 16 + l16) * 16);
      }
      if (grp == 0) {
        #pragma unroll
        for (int c = 0; c < 4; ++c)
          s2v[c] = s2g[mtg * 128 + wc * 64 + c * 16 + l16];
      }
      // b2 loads for the NEXT (even) slot's gemm2; dummy (clamped) at mt0
      if ((grp & 1) == 1 && !(mt == 7 && grp == 7)) {
        int ks, sm;
        if (grp < 7) { ks = (grp + 1) >> 1; sm = mtg - 1; }
        else         { ks = 0;              sm = mtg;     }
        if (sm < 0) sm = 0;
        const int kg = ks * 4 + quad;
        const size_t sb = (size_t)(sm * 16 + kg);
        #pragma unroll
        for (int c = 0; c < 4; ++c)
          b2[c] = ldg_b128(hw_ws + (sb * 128 + wc * 64 + c * 16 + l16) * 8);
      }

      SB0();   // pin region loads above, stage below (stage = newest in vm queue)

      if (grp <= 4)     stage_grp(mt, grp + 3);
      else if (mt < 7)  stage_grp(mt + 1, grp - 5);

      if (grp == 0)              WAITLG(6);
      else if ((grp & 1) == 0)   { if (mt < 7 || grp < 6) WAITLG(2); else WAITLG(0); }
      else if (grp == 7)         { if (mt < 7) WAITLG(7); else WAITLG(0); }
      else                       WAITLG(7);   // grps 1,3,5

      __builtin_amdgcn_s_barrier();
      SB0();

      // ---- post-barrier: pure-register MFMA burst ----
      __builtin_amdgcn_s_setprio(1);
      #pragma unroll
      for (int k2 = 0; k2 < 2; ++k2)
        #pragma unroll
        for (int c = 0; c < 4; ++c)
          acc_xs[c] = __builtin_amdgcn_mfma_f32_16x16x32_fp8_fp8(a[k2], bf[k2][c],
                                                                 acc_xs[c], 0, 0, 0);
      if (mt > 0 && (grp & 1) == 0) {
        #pragma unroll
        for (int c = 0; c < 4; ++c)
          acc_out[c] = __builtin_amdgcn_mfma_f32_16x16x32_bf16(a2, b2[c], acc_out[c], 0, 0, 0);
      }
      __builtin_amdgcn_s_setprio(0);
    }

    // ---- epilogue: t = acc + x2g + s2g ; k = min(exp2(-t),1) -> bf16 Ks ----
    #pragma unroll
    for (int c = 0; c < 4; ++c) {
      const int cl = wc * 64 + c * 16 + l16;       // m-col 0..127
      char* kbase = smem + 65536 + (cl >> 3) * 1024 + (cl & 7) * 2;
      #pragma unroll
      for (int i = 0; i < 4; ++i) {
        const int row = wr * 16 + quad * 4 + i;
        const float t = acc_xs[c][i] + x2v[i] + s2v[c];
        float kv = __builtin_amdgcn_exp2f(-t);
        kv = fminf(kv, 1.0f);
        *(u16*)(kbase + row * 16) = (u16)(__float_as_uint(kv) >> 16);
        acc_xs[c][i] = 0.0f;
      }
    }
    // lgkm-only barrier: Ks writes ordered before next mt's a2 reads; stages stay in flight
    asm volatile("s_waitcnt lgkmcnt(0)" ::: "memory");
    SB0();
    __builtin_amdgcn_s_barrier();
    SB0();
  }

  // ---- drained GEMM2 for the last mtile ----
  #pragma unroll
  for (int ks = 0; ks < 4; ++ks) {
    const int kg = ks * 4 + quad;
    const size_t sb = (size_t)((half * 8 + 7) * 16 + kg);
    bf16x8 bb[4];
    #pragma unroll
    for (int c = 0; c < 4; ++c)
      bb[c] = *(const bf16x8*)(hw_ws + (sb * 128 + wc * 64 + c * 16 + l16) * 8);
    bf16x8 a2 = *(const bf16x8*)(smem + 65536 + kg * 1024 + (wr * 16 + l16) * 16);
    #pragma unroll
    for (int c = 0; c < 4; ++c)
      acc_out[c] = __builtin_amdgcn_mfma_f32_16x16x32_bf16(a2, bb[c], acc_out[c], 0, 0, 0);
  }

  // ---- final: atomic-accumulate scale*acc (+ bias/shift once, by half==0 blocks) ----
  float addv[4];
  #pragma unroll
  for (int c = 0; c < 4; ++c) {
    const int col = wc * 64 + c * 16 + l16;
    addv[c] = (half == 0) ? (vscale * head_b[col] + vshift) : 0.0f;
  }
  #pragma unroll
  for (int c = 0; c < 4; ++c) {
    const int col = wc * 64 + c * 16 + l16;
    #pragma unroll
    for (int i = 0; i < 4; ++i) {
      const int row = b0 + wr * 16 + quad * 4 + i;
      atomicAdd(&out[(size_t)row * NOUT + col], vscale * acc_out[c][i] + addv[c]);
    }
  }
}

// ---------- launch ----------
extern "C" void kernel_launch(void* const* d_in, const int* in_sizes, int n_in,
                              void* d_out, int out_size, void* d_ws, size_t ws_size,
                              hipStream_t stream) {
  const float* x       = (const float*)d_in[0];
  const float* support = (const float*)d_in[1];
  const float* gamma   = (const float*)d_in[2];
  const float* head_w  = (const float*)d_in[3];
  const float* head_b  = (const float*)d_in[4];
  const float* scale   = (const float*)d_in[5];
  const float* shift   = (const float*)d_in[6];
  float* out = (float*)d_out;

  char* w = (char*)d_ws;
  u8*    x_ws  = (u8*)(w);                        //  8,388,608 B
  u8*    s_ws  = (u8*)(w + 8388608);              //  2,097,152 B
  u16*   hw_ws = (u16*)(w + 10485760);            //  1,048,576 B
  float* x2g   = (float*)(w + 11534336);          //     65,536 B
  float* s2g   = (float*)(w + 11599872);          //     16,384 B

  static bool lds_init = false;
  if (!lds_init) {
    hipFuncSetAttribute(reinterpret_cast<const void*>(rbf_fused),
                        hipFuncAttributeMaxDynamicSharedMemorySize, 81920);
    lds_init = true;
  }

  prep_all<<<736, 256, 0, stream>>>(x, support, head_w, gamma,
                                    x_ws, s_ws, hw_ws, x2g, s2g, out);
  rbf_fused<<<1024, 512, 81920, stream>>>(x_ws, s_ws, hw_ws, x2g, s2g,
                                          head_b, scale, shift, out);
}

// Round 5
// 182.325 us; speedup vs baseline: 1.2382x; 1.1637x over previous
//
#include <hip/hip_runtime.h>

typedef unsigned int u32;
typedef unsigned short u16;
typedef unsigned char u8;
typedef __attribute__((ext_vector_type(8))) __bf16 bf16x8;
typedef __attribute__((ext_vector_type(4))) float f32x4;
typedef __attribute__((ext_vector_type(4))) int i32x4;

#define NB 16384
#define NM 4096
#define ND 512
#define NOUT 128
#define L2E 1.44269504088896340736f

// ws layout: x_ws fp8 [rb(256)][kg64(64)][row(64)][8B]   (8 MB)
//            s_ws fp8 [mb(32)][kg64(64)][m(128)][8B]     (2 MB, pre-scaled by -2*gamma*log2e)
//            hw_ws bf16 [slab=(mb*16+kg)][o(128)][8]     (1 MB)
// x2g[16384] = gamma*log2e*||x||^2 ; s2g[4096] = gamma*log2e*||s||^2  (fp32-exact)

#define WAITLG(N) do { asm volatile("s_waitcnt vmcnt(" #N ") lgkmcnt(0)" ::: "memory"); \
                       __builtin_amdgcn_sched_barrier(0); } while (0)
#define SB0() __builtin_amdgcn_sched_barrier(0)

// ---------- helpers ----------
__device__ __forceinline__ u16 f2bf(float f) {
  u32 u = __float_as_uint(f);
  u += 0x7FFFu + ((u >> 16) & 1u);   // RNE
  return (u16)(u >> 16);
}

// manual fp32 -> e4m3fn (RNE, flush |v|<2^-6 to 0; |v| <= ~15 here so no sat needed)
__device__ __forceinline__ u8 f2fp8(float f) {
  u32 u = __float_as_uint(f);
  u32 s = (u >> 24) & 0x80u;
  u32 au = u & 0x7FFFFFFFu;
  if (au < 0x3C800000u) return (u8)s;          // below min normal -> 0
  au += 0x000FFFFFu + ((au >> 20) & 1u);       // RNE to 3 mantissa bits
  u32 e = (au >> 23) - 120u;                   // rebias 127 -> 7
  u32 m = (au >> 20) & 7u;
  return (u8)(s | (e << 3) | m);
}

__device__ __forceinline__ void stage16(const void* g, void* l) {
  __builtin_amdgcn_global_load_lds((__attribute__((address_space(1))) void*)g,
                                   (__attribute__((address_space(3))) void*)l,
                                   16, 0, 0);
}

// compiler-invisible b128 global load: no forced compiler vmcnt before the
// consumer; my counted waits cover it (HW vmcnt counts asm loads too)
__device__ __forceinline__ bf16x8 ldg_b128(const void* p) {
  i32x4 r;
  asm volatile("global_load_dwordx4 %0, %1, off" : "=&v"(r) : "v"(p) : "memory");
  return __builtin_bit_cast(bf16x8, r);
}

__device__ __forceinline__ uint4 pack8bf(float4 v0, float4 v1) {
  uint4 pk;
  pk.x = (u32)f2bf(v0.x) | ((u32)f2bf(v0.y) << 16);
  pk.y = (u32)f2bf(v0.z) | ((u32)f2bf(v0.w) << 16);
  pk.z = (u32)f2bf(v1.x) | ((u32)f2bf(v1.y) << 16);
  pk.w = (u32)f2bf(v1.z) | ((u32)f2bf(v1.w) << 16);
  return pk;
}

__device__ __forceinline__ uint2 pack8f8(float4 v0, float4 v1) {
  uint2 pk;
  pk.x = (u32)f2fp8(v0.x) | ((u32)f2fp8(v0.y) << 8) |
         ((u32)f2fp8(v0.z) << 16) | ((u32)f2fp8(v0.w) << 24);
  pk.y = (u32)f2fp8(v1.x) | ((u32)f2fp8(v1.y) << 8) |
         ((u32)f2fp8(v1.z) << 16) | ((u32)f2fp8(v1.w) << 24);
  return pk;
}

// ---------- merged prep ----------
// blocks [0,512): x tiles (fp8)   [512,640): support tiles (fp8, scaled)
// [640,672): head_w (bf16)        [672,736): zero d_out (64 blocks x 128 KB)
__global__ __launch_bounds__(256) void prep_all(const float* __restrict__ x,
                                                const float* __restrict__ s,
                                                const float* __restrict__ hw,
                                                const float* __restrict__ gamma_p,
                                                u8*  __restrict__ x_ws,
                                                u8*  __restrict__ s_ws,
                                                u16* __restrict__ hw_ws,
                                                float* __restrict__ x2g,
                                                float* __restrict__ s2g,
                                                float* __restrict__ out) {
  __shared__ uint2 t8[2048];       // 16 KB (x/s transpose, XOR-swizzled)
  __shared__ uint4 t16[2048];      // 32 KB (hw transpose)
  const int tid = threadIdx.x, bid = blockIdx.x;
  const int lane = tid & 63, w = tid >> 6;

  if (bid < 640) {
    const bool isx = bid < 512;
    const int blk = isx ? bid : (bid - 512);
    const float* src_m = isx ? x : s;
    u8*    dst_ws = isx ? x_ws : s_ws;
    float* sq_out = isx ? x2g : s2g;
    const float gl   = gamma_p[0] * L2E;
    const float cmul = isx ? 1.0f : (-2.0f * gl);
    const int big  = isx ? (blk >> 1) : (blk >> 2);
    const int roff = isx ? ((blk & 1) * 32) : ((blk & 3) * 32);
    const int rows = isx ? 64 : 128;

    #pragma unroll
    for (int p = 0; p < 8; ++p) {
      const int row = p * 4 + w;                      // local row 0..31
      const float* src = src_m + (size_t)(blk * 32 + row) * ND + lane * 8;
      float4 v0 = *(const float4*)src;
      float4 v1 = *(const float4*)(src + 4);
      float ss = v0.x*v0.x + v0.y*v0.y + v0.z*v0.z + v0.w*v0.w
               + v1.x*v1.x + v1.y*v1.y + v1.z*v1.z + v1.w*v1.w;
      #pragma unroll
      for (int off = 32; off > 0; off >>= 1) ss += __shfl_down(ss, off);
      if (lane == 0) sq_out[blk * 32 + row] = gl * ss;
      v0.x *= cmul; v0.y *= cmul; v0.z *= cmul; v0.w *= cmul;
      v1.x *= cmul; v1.y *= cmul; v1.z *= cmul; v1.w *= cmul;
      t8[lane * 32 + ((row + lane) & 31)] = pack8f8(v0, v1);   // kg = lane
    }
    __syncthreads();
    #pragma unroll
    for (int p = 0; p < 8; ++p) {
      const int kg = p * 8 + (tid >> 5);
      const int row = tid & 31;
      uint2 pk = t8[kg * 32 + ((row + kg) & 31)];
      *(uint2*)&dst_ws[(((size_t)(big * 64 + kg)) * rows + roff + row) * 8] = pk;
    }
  } else if (bid < 672) {
    // ---- head_w: m-chunk of 128 (bf16) ----
    const int blk = bid - 640;
    #pragma unroll
    for (int p = 0; p < 8; ++p) {
      const int o = p * 16 + (tid >> 4);
      const int kg = tid & 15;
      const float* src = hw + (size_t)o * NM + blk * 128 + kg * 8;
      float4 v0 = *(const float4*)src;
      float4 v1 = *(const float4*)(src + 4);
      t16[o * 16 + ((kg + o) & 15)] = pack8bf(v0, v1);
    }
    __syncthreads();
    #pragma unroll
    for (int it = 0; it < 8; ++it) {
      const int kg = it * 2 + (tid >> 7);
      const int o = tid & 127;
      uint4 pk = t16[o * 16 + ((kg + o) & 15)];
      *(uint4*)&hw_ws[(((size_t)(blk * 16 + kg)) * 128 + o) * 8] = pk;
    }
  } else {
    // ---- zero d_out: 64 blocks x 128 KB ----
    float4* o4 = (float4*)out;
    const float4 z = {0.f, 0.f, 0.f, 0.f};
    size_t base = (size_t)(bid - 672) * 8192 + tid;
    #pragma unroll 8
    for (int i = 0; i < 32; ++i) o4[base + (size_t)i * 256] = z;
  }
}

// ---------- main fused kernel ----------
// R5 = R2 config (256 thr, 4 waves, 32x64 wave tile, 80KB LDS: X 32K @0,
// Sbuf ring 4x8K @32768, Ks 16K @65536, 2 blk/CU) with a REGISTER
// double-buffered fragment pipeline + MFMA/ds_read interleave:
//   slot t: [barrier] {8 fp8 MFMA(t)} {6 ds_read(t+1)} {8 fp8 MFMA(t)}
//           {6 ds_read(t+1)} {gemm2 (even,mt>0)} {stage(t+3); b2(t+2,even)}
//           [WAITLG(N)] -> next
// MFMA(t) consumes regs read during slot t-1 => no lgkm on the MFMA path;
// the ds_reads issue inside the MFMA pipe-stall gaps (SB0-pinned chunks) —
// the AITER 1:1 interleave, fixing R2's convoy (slot 1500cyc vs 610 matrix).
// Wait table (exact; queue = per-thread vmem FIFO, order pinned by SB0):
//   steady: even slots N=6 (drain S(t+2) [+s2v @grp0]), odd N=2 (drain
//   S(t+2)+b2);  prologue vmcnt(2); mt7 tail g5/g6/g7 = 0.
// a2 (Ks) hoisted per-mt AFTER the epilogue barrier (cross-wave Ks dep);
// b2 double-buffered, issued 2 slots ahead (drained by the odd-N=2 wait one
// slot before use). VGPR ~210 is free: LDS caps at 2 blk/CU = 2 waves/SIMD,
// which supports up to 256 VGPR (m69). launch_bounds(256,2) as R2.
__global__ __launch_bounds__(256, 2)
void rbf_fused(const u8* __restrict__ x_ws, const u8* __restrict__ s_ws,
               const u16* __restrict__ hw_ws, const float* __restrict__ x2g,
               const float* __restrict__ s2g, const float* __restrict__ head_b,
               const float* __restrict__ scale_p, const float* __restrict__ shift_p,
               float* __restrict__ out)
{
  extern __shared__ __align__(16) char smem[];   // 80 KB dynamic

  const int tid  = threadIdx.x;
  const int w    = tid >> 6;
  const int lane = tid & 63;
  const int quad = lane >> 4;
  const int l16  = lane & 15;
  const int wr   = w & 1;    // row half (32 rows)
  const int wc   = w >> 1;   // m / out-col half (64)
  const int xcd  = blockIdx.x & 7;
  const int rb   = (blockIdx.x >> 3) * 2 + (xcd & 1);
  const int half = xcd >> 1;
  const int b0   = rb * 64;

  const float vscale = scale_p[0];
  const float vshift = shift_p[0];

  const u8* xsrc = x_ws + (size_t)rb * 32768;
  const u8* ssrc = s_ws + (size_t)(half * 8) * 65536;

  auto stage_grp = [&](int mt_s, int grp_s) {
    const u8* sp = ssrc + (size_t)mt_s * 65536 + grp_s * 8192;
    char* dp = smem + 32768 + (grp_s & 3) * 8192;
    stage16(sp + tid * 16, dp + tid * 16);
    stage16(sp + 4096 + tid * 16, dp + 4096 + tid * 16);
  };

  // ---- prologue: x2v, X->LDS, S0..S2; queue = [x2v:2, X:8, S0:2, S1:2, S2:2]
  f32x4 x2v[2];
  #pragma unroll
  for (int r = 0; r < 2; ++r)
    x2v[r] = *(const f32x4*)&x2g[b0 + wr * 32 + r * 16 + quad * 4];
  SB0();
  #pragma unroll
  for (int i = 0; i < 8; ++i)
    stage16(xsrc + i * 4096 + tid * 16, smem + i * 4096 + tid * 16);
  SB0();
  stage_grp(0, 0); SB0();
  stage_grp(0, 1); SB0();
  stage_grp(0, 2);
  asm volatile("s_waitcnt vmcnt(2)" ::: "memory");  // drains x2v,X,S0,S1; S2 in flight
  SB0();
  __builtin_amdgcn_s_barrier();
  SB0();

  // fragment register double-buffers
  long long aF[2][2][2];     // [parity][k2][r]
  long long bF[2][2][4];     // [parity][k2][c]
  bf16x8 b2[2][4];           // gemm2 B, issued 2 slots ahead
  bf16x8 a2h[4][2];          // Ks slabs for this mt (hoisted)

  // ---- reads(slot 0) into parity 0 ----
  #pragma unroll
  for (int k2 = 0; k2 < 2; ++k2) {
    #pragma unroll
    for (int r = 0; r < 2; ++r)
      aF[0][k2][r] = *(const long long*)(smem + ((k2 * 4 + quad) * 64 + wr * 32 + r * 16 + l16) * 8);
    #pragma unroll
    for (int c = 0; c < 4; ++c)
      bF[0][k2][c] = *(const long long*)(smem + 32768 +
                       ((k2 * 4 + quad) * 128 + wc * 64 + c * 16 + l16) * 8);
  }
  asm volatile("s_waitcnt lgkmcnt(0)" ::: "memory");
  SB0();

  const f32x4 zf = {0.f, 0.f, 0.f, 0.f};
  f32x4 acc_xs[2][4];
  f32x4 acc_out[2][4];
  #pragma unroll
  for (int r = 0; r < 2; ++r)
    #pragma unroll
    for (int c = 0; c < 4; ++c) { acc_xs[r][c] = zf; acc_out[r][c] = zf; }

  #pragma unroll 1
  for (int mt = 0; mt < 8; ++mt) {
    const int mtg = half * 8 + mt;

    // ---- mt-top: a2 hoist (after epilogue barrier => Ks(mt-1) visible) ----
    if (mt > 0) {
      #pragma unroll
      for (int ks = 0; ks < 4; ++ks) {
        const int kg = ks * 4 + quad;
        #pragma unroll
        for (int r = 0; r < 2; ++r)
          a2h[ks][r] = *(const bf16x8*)(smem + 65536 + (kg * 64 + wr * 32 + r * 16 + l16) * 16);
      }
      asm volatile("s_waitcnt lgkmcnt(0)" ::: "memory");
      SB0();
    }
    // s2v rides the vm queue; drained by slot-0's N=6 wait
    float s2v[4];
    #pragma unroll
    for (int c = 0; c < 4; ++c)
      s2v[c] = s2g[mtg * 128 + wc * 64 + c * 16 + l16];
    SB0();

    #pragma unroll
    for (int grp = 0; grp < 8; ++grp) {
      const int p  = grp & 1;
      const int pn = p ^ 1;
      const int gN = grp + 1;                 // next slot (8 => (mt+1,0))
      const bool doRd = !(mt == 7 && grp == 7);

      // ---- MFMA chunk 1: k2=0 (8 fp8) ----
      __builtin_amdgcn_s_setprio(1);
      #pragma unroll
      for (int r = 0; r < 2; ++r)
        #pragma unroll
        for (int c = 0; c < 4; ++c)
          acc_xs[r][c] = __builtin_amdgcn_mfma_f32_16x16x32_fp8_fp8(
              aF[p][0][r], bF[p][0][c], acc_xs[r][c], 0, 0, 0);
      __builtin_amdgcn_s_setprio(0);
      SB0();
      // ---- reads chunk 1 (t+1): 4 aF + 2 bF ----
      if (doRd) {
        #pragma unroll
        for (int k2 = 0; k2 < 2; ++k2)
          #pragma unroll
          for (int r = 0; r < 2; ++r)
            aF[pn][k2][r] = *(const long long*)(smem +
                ((((gN & 7) * 2 + k2) * 4 + quad) * 64 + wr * 32 + r * 16 + l16) * 8);
        #pragma unroll
        for (int c = 0; c < 2; ++c)
          bF[pn][0][c] = *(const long long*)(smem + 32768 + (gN & 3) * 8192 +
              ((0 * 4 + quad) * 128 + wc * 64 + c * 16 + l16) * 8);
      }
      SB0();
      // ---- MFMA chunk 2: k2=1 (8 fp8) ----
      __builtin_amdgcn_s_setprio(1);
      #pragma unroll
      for (int r = 0; r < 2; ++r)
        #pragma unroll
        for (int c = 0; c < 4; ++c)
          acc_xs[r][c] = __builtin_amdgcn_mfma_f32_16x16x32_fp8_fp8(
              aF[p][1][r], bF[p][1][c], acc_xs[r][c], 0, 0, 0);
      __builtin_amdgcn_s_setprio(0);
      SB0();
      // ---- reads chunk 2 (t+1): 6 bF ----
      if (doRd) {
        #pragma unroll
        for (int c = 2; c < 4; ++c)
          bF[pn][0][c] = *(const long long*)(smem + 32768 + (gN & 3) * 8192 +
              ((0 * 4 + quad) * 128 + wc * 64 + c * 16 + l16) * 8);
        #pragma unroll
        for (int c = 0; c < 4; ++c)
          bF[pn][1][c] = *(const long long*)(smem + 32768 + (gN & 3) * 8192 +
              ((1 * 4 + quad) * 128 + wc * 64 + c * 16 + l16) * 8);
      }
      SB0();
      // ---- gemm2 (even slots, mt>0): regs only ----
      if (mt > 0 && (grp & 1) == 0) {
        __builtin_amdgcn_s_setprio(1);
        #pragma unroll
        for (int r = 0; r < 2; ++r)
          #pragma unroll
          for (int c = 0; c < 4; ++c)
            acc_out[r][c] = __builtin_amdgcn_mfma_f32_16x16x32_bf16(
                a2h[grp >> 1][r], b2[(grp >> 1) & 1][c], acc_out[r][c], 0, 0, 0);
        __builtin_amdgcn_s_setprio(0);
      }
      SB0();
      // ---- stage(t+3) then b2(t+2) (even slots) ----
      if (grp <= 4)     stage_grp(mt, grp + 3);
      else if (mt < 7)  stage_grp(mt + 1, grp - 5);
      if ((grp & 1) == 0 && !(mt == 7 && grp == 6)) {
        const int gs = (grp + 2) & 7;
        const int ms = mt + (grp == 6);
        int sl = half * 8 + ms - 1; if (sl < 0) sl = 0;   // dummy at mt0 head
        const int kg = (gs >> 1) * 4 + quad;
        const size_t sb = (size_t)(sl * 16 + kg);
        #pragma unroll
        for (int c = 0; c < 4; ++c)
          b2[((grp >> 1) + 1) & 1][c] = ldg_b128(hw_ws + (sb * 128 + wc * 64 + c * 16 + l16) * 8);
      }

      // ---- counted wait + barrier ----
      if (mt == 7 && grp >= 5)   WAITLG(0);
      else if ((grp & 1) == 0)   WAITLG(6);
      else                       WAITLG(2);
      __builtin_amdgcn_s_barrier();
      SB0();
    }

    // ---- epilogue: t = acc + x2g + s2g ; k = min(exp2(-t),1) -> bf16 Ks ----
    {
      #pragma unroll
      for (int r = 0; r < 2; ++r)
        #pragma unroll
        for (int c = 0; c < 4; ++c) {
          const int cl = wc * 64 + c * 16 + l16;     // m-col 0..127
          char* kbase = smem + 65536 + (cl >> 3) * 1024 + (cl & 7) * 2;
          #pragma unroll
          for (int i = 0; i < 4; ++i) {
            const int row = wr * 32 + r * 16 + quad * 4 + i;
            const float t = acc_xs[r][c][i] + x2v[r][i] + s2v[c];
            float kv = __builtin_amdgcn_exp2f(-t);
            kv = fminf(kv, 1.0f);
            *(u16*)(kbase + row * 16) = (u16)(__float_as_uint(kv) >> 16);
            acc_xs[r][c][i] = 0.0f;
          }
        }
    }
    // lgkm-only barrier: Ks writes ordered before a2 hoist of mt+1; in-flight
    // stages for mt+1 stay in flight
    asm volatile("s_waitcnt lgkmcnt(0)" ::: "memory");
    SB0();
    __builtin_amdgcn_s_barrier();
    SB0();
  }

  // ---- drained GEMM2 for the last mtile ----
  #pragma unroll
  for (int ks = 0; ks < 4; ++ks) {
    const int kg = ks * 4 + quad;
    const size_t sb = (size_t)((half * 8 + 7) * 16 + kg);
    bf16x8 bb[4], a2[2];
    #pragma unroll
    for (int c = 0; c < 4; ++c)
      bb[c] = *(const bf16x8*)(hw_ws + (sb * 128 + wc * 64 + c * 16 + l16) * 8);
    #pragma unroll
    for (int r = 0; r < 2; ++r)
      a2[r] = *(const bf16x8*)(smem + 65536 + (kg * 64 + wr * 32 + r * 16 + l16) * 16);
    #pragma unroll
    for (int r = 0; r < 2; ++r)
      #pragma unroll
      for (int c = 0; c < 4; ++c)
        acc_out[r][c] = __builtin_amdgcn_mfma_f32_16x16x32_bf16(a2[r], bb[c], acc_out[r][c], 0, 0, 0);
  }

  // ---- final: atomic-accumulate scale*acc (+ bias/shift once, by half==0 blocks) ----
  float addv[4];
  #pragma unroll
  for (int c = 0; c < 4; ++c) {
    const int col = wc * 64 + c * 16 + l16;
    addv[c] = (half == 0) ? (vscale * head_b[col] + vshift) : 0.0f;
  }
  #pragma unroll
  for (int r = 0; r < 2; ++r)
    #pragma unroll
    for (int c = 0; c < 4; ++c) {
      const int col = wc * 64 + c * 16 + l16;
      #pragma unroll
      for (int i = 0; i < 4; ++i) {
        const int row = b0 + wr * 32 + r * 16 + quad * 4 + i;
        atomicAdd(&out[(size_t)row * NOUT + col], vscale * acc_out[r][c][i] + addv[c]);
      }
    }
}

// ---------- launch ----------
extern "C" void kernel_launch(void* const* d_in, const int* in_sizes, int n_in,
                              void* d_out, int out_size, void* d_ws, size_t ws_size,
                              hipStream_t stream) {
  const float* x       = (const float*)d_in[0];
  const float* support = (const float*)d_in[1];
  const float* gamma   = (const float*)d_in[2];
  const float* head_w  = (const float*)d_in[3];
  const float* head_b  = (const float*)d_in[4];
  const float* scale   = (const float*)d_in[5];
  const float* shift   = (const float*)d_in[6];
  float* out = (float*)d_out;

  char* w = (char*)d_ws;
  u8*    x_ws  = (u8*)(w);                        //  8,388,608 B
  u8*    s_ws  = (u8*)(w + 8388608);              //  2,097,152 B
  u16*   hw_ws = (u16*)(w + 10485760);            //  1,048,576 B
  float* x2g   = (float*)(w + 11534336);          //     65,536 B
  float* s2g   = (float*)(w + 11599872);          //     16,384 B

  static bool lds_init = false;
  if (!lds_init) {
    hipFuncSetAttribute(reinterpret_cast<const void*>(rbf_fused),
                        hipFuncAttributeMaxDynamicSharedMemorySize, 81920);
    lds_init = true;
  }

  prep_all<<<736, 256, 0, stream>>>(x, support, head_w, gamma,
                                    x_ws, s_ws, hw_ws, x2g, s2g, out);
  rbf_fused<<<1024, 256, 81920, stream>>>(x_ws, s_ws, hw_ws, x2g, s2g,
                                          head_b, scale, shift, out);
}